// Round 13
// baseline (387.815 us; speedup 1.0000x reference)
//
#include <hip/hip_runtime.h>
#include <hip/hip_bf16.h>
#include <hip/hip_fp16.h>

#define E4M3_MAX 240.0f

typedef __attribute__((ext_vector_type(8))) __bf16 bf16x8;
typedef __attribute__((ext_vector_type(16))) float f32x16;
typedef unsigned short ushort_t;

__device__ __forceinline__ void gload_lds16(const void* g, void* l) {
  __builtin_amdgcn_global_load_lds(
      (const __attribute__((address_space(1))) void*)g,
      (__attribute__((address_space(3))) void*)l,
      16, 0, 0);
}

// ---------------- amax over |weight| ----------------
__global__ void amax_abs_kernel(const float* __restrict__ w, int n4,
                                unsigned* __restrict__ amax_bits) {
  float m = 0.0f;
  const float4* w4 = (const float4*)w;
  int stride = gridDim.x * blockDim.x;
  for (int i = blockIdx.x * blockDim.x + threadIdx.x; i < n4; i += stride) {
    float4 v = w4[i];
    m = fmaxf(m, fmaxf(fmaxf(fabsf(v.x), fabsf(v.y)),
                       fmaxf(fabsf(v.z), fabsf(v.w))));
  }
  for (int off = 32; off > 0; off >>= 1)
    m = fmaxf(m, __shfl_down(m, off, 64));
  __shared__ float smax[4];
  int l = threadIdx.x & 63, wv = threadIdx.x >> 6;
  if (l == 0) smax[wv] = m;
  __syncthreads();
  if (threadIdx.x == 0) {
    float bm = fmaxf(fmaxf(smax[0], smax[1]), fmaxf(smax[2], smax[3]));
    atomicMax(amax_bits, __float_as_uint(bm));
  }
}

// ---------------- quantize weight -> bf16 qw ----------------
__global__ void quant_weight_kernel(const float* __restrict__ w,
                                    const unsigned* __restrict__ amax_bits,
                                    ushort_t* __restrict__ qw, int n4) {
  float amax = __uint_as_float(*amax_bits);
  float scale = fmaxf(amax / E4M3_MAX, 1e-10f);
  const float4* w4 = (const float4*)w;
  ushort4* q4 = (ushort4*)qw;
  int stride = gridDim.x * blockDim.x;
  for (int i = blockIdx.x * blockDim.x + threadIdx.x; i < n4; i += stride) {
    float4 v = w4[i];
    float r[4] = {v.x, v.y, v.z, v.w};
    ushort_t o[4];
#pragma unroll
    for (int j = 0; j < 4; ++j) {
      float s = fminf(fmaxf(r[j] / scale, -E4M3_MAX), E4M3_MAX);
      s = __half2float(__float2half(s));   // fp16 round-trip (RNE)
      float q = rintf(s * 8.0f) * 0.125f;  // mantissa grid, half-to-even
      q = fminf(fmaxf(q, -E4M3_MAX), E4M3_MAX);
      __hip_bfloat16 h = __float2bfloat16(q * scale);
      o[j] = *(ushort_t*)&h;
    }
    ushort4 ov = {o[0], o[1], o[2], o[3]};
    q4[i] = ov;
  }
}

// ---------------- convert x fp32 -> bf16 ----------------
__global__ void cvt_bf16_kernel(const float* __restrict__ x,
                                ushort_t* __restrict__ xb, int n4) {
  const float4* x4 = (const float4*)x;
  ushort4* o4 = (ushort4*)xb;
  int stride = gridDim.x * blockDim.x;
  for (int i = blockIdx.x * blockDim.x + threadIdx.x; i < n4; i += stride) {
    float4 v = x4[i];
    __hip_bfloat16 h0 = __float2bfloat16(v.x);
    __hip_bfloat16 h1 = __float2bfloat16(v.y);
    __hip_bfloat16 h2 = __float2bfloat16(v.z);
    __hip_bfloat16 h3 = __float2bfloat16(v.w);
    ushort4 o = {*(ushort_t*)&h0, *(ushort_t*)&h1,
                 *(ushort_t*)&h2, *(ushort_t*)&h3};
    o4[i] = o;
  }
}

// == 128x128 bf16 GEMM — 32x32x16, σ-swizzle, 64KB LDS -> 2 blocks/CU ==
// C = A * Bt^T + bias.  A: [8192][4096] bf16, Bt: [4096][4096] bf16, C fp32.
// 4 waves/block (2x2), per wave 64x64, BK=64, dbuf LDS 64 KiB.
// Single-phase tile: stage(u+1)->cb^1 (certified by prev end-BAR); 16 ds_reads;
// LGKM4 -> MMA rg0; LGKM0 -> MMA rg1; VMC0; BAR.  Per-block stalls are covered
// by the SECOND resident block on each SIMD (m114 co-scheduling) — the variable
// all 1-block/CU rounds (R2-R12, 38-47% MfmaUtil) never exercised.

#define BAR() do { asm volatile("" ::: "memory"); \
                   __builtin_amdgcn_s_barrier(); \
                   asm volatile("" ::: "memory"); } while (0)
#define FEN() asm volatile("" ::: "memory")
#define LGKM0() asm volatile("s_waitcnt lgkmcnt(0)" ::: "memory")
#define LGKM4() asm volatile("s_waitcnt lgkmcnt(4)" ::: "memory")
#define VMC0() asm volatile("s_waitcnt vmcnt(0)" ::: "memory")
#define NOVM() do {} while (0)

__global__ __launch_bounds__(256, 2) void gemm128_2b(
    const ushort_t* __restrict__ A, const ushort_t* __restrict__ Bt,
    const float* __restrict__ bias, float* __restrict__ C) {
  constexpr int K = 4096, N = 4096;
  // [buf][128 rows][64 cols] bf16 = 16 KB per buf per matrix -> 64 KB total
  __shared__ __align__(16) ushort_t As[2][8192];
  __shared__ __align__(16) ushort_t Bs[2][8192];

  const int tid = threadIdx.x;
  const int wid = tid >> 6, lane = tid & 63;
  const int wm = wid >> 1, wn = wid & 1;     // 2 x 2 wave grid
  const int l31 = lane & 31, lk2 = lane >> 5;

  // XCD swizzle (nwg = 2048, divisible by 8)
  int bid = blockIdx.x;
  int swz = (bid & 7) * 256 + (bid >> 3);
  int bm = swz >> 5, bn = swz & 31;          // nbn = 32

  const ushort_t* Ab = A + (size_t)bm * 128 * K;
  const ushort_t* Bb = Bt + (size_t)bn * 128 * K;

  // staging: slot s = q*256+tid (q=0..3); row = s>>3; granule c = (s&7)^σ(row),
  // σ(r) = (r&7) ^ ((r>>3)&3)
  int offG[4];
#pragma unroll
  for (int q = 0; q < 4; ++q) {
    int s = q * 256 + tid;
    int row = s >> 3;
    int c = (s & 7) ^ (row & 7) ^ ((row >> 3) & 3);
    offG[q] = row * K + c * 8;
  }

  // stage one full 128x64 tile of A or B (4 gloads each)
#define STAGE_A(buf, kt)                                                   \
  do { _Pragma("unroll") for (int q = 0; q < 4; ++q)                       \
    gload_lds16(Ab + (size_t)(kt) * 64 + offG[q],                          \
                &As[buf][(q * 256 + tid) * 8 - lane * 8]); } while (0)
#define STAGE_B(buf, kt)                                                   \
  do { _Pragma("unroll") for (int q = 0; q < 4; ++q)                       \
    gload_lds16(Bb + (size_t)(kt) * 64 + offG[q],                          \
                &Bs[buf][(q * 256 + tid) * 8 - lane * 8]); } while (0)
  // note: dest expr is wave-uniform base (q*256 + wid*64)*8; written as
  // (q*256+tid)*8 - lane*8 so it stays formally uniform per lane group.

  // swizzled ds_read: granule = (ks*2 + lk2) ^ σ(row); row bases (wm*64,
  // wn*64, rg*32, cg*32) are multiples of 32 -> σ(row) is lane-constant.
  const int sig = (l31 & 7) ^ ((l31 >> 3) & 3);
  int xks[4];
#pragma unroll
  for (int ks = 0; ks < 4; ++ks) xks[ks] = ((ks * 2 + lk2) ^ sig) * 8;

  bf16x8 af[2][4], bf[2][4];
  f32x16 acc[2][2] = {};

#define RD_B2(cb)                                                          \
  do { _Pragma("unroll") for (int cg = 0; cg < 2; ++cg)                    \
    _Pragma("unroll") for (int ks = 0; ks < 4; ++ks)                       \
      bf[cg][ks] = *(const bf16x8*)                                        \
          &Bs[cb][(wn * 64 + cg * 32 + l31) * 64 + xks[ks]]; } while (0)
#define RD_A1(cb, rg)                                                      \
  do { _Pragma("unroll") for (int ks = 0; ks < 4; ++ks)                    \
    af[rg][ks] = *(const bf16x8*)                                          \
        &As[cb][(wm * 64 + (rg) * 32 + l31) * 64 + xks[ks]]; } while (0)

  // 8 MFMA: one A row-group x both col-groups x K=64
#define MMA8(rg)                                                           \
  do { __builtin_amdgcn_s_setprio(1);                                      \
    _Pragma("unroll") for (int ks = 0; ks < 4; ++ks) {                     \
      acc[rg][0] = __builtin_amdgcn_mfma_f32_32x32x16_bf16(                \
          af[rg][ks], bf[0][ks], acc[rg][0], 0, 0, 0);                     \
      acc[rg][1] = __builtin_amdgcn_mfma_f32_32x32x16_bf16(                \
          af[rg][ks], bf[1][ks], acc[rg][1], 0, 0, 0);                     \
    }                                                                      \
    __builtin_amdgcn_s_setprio(0); } while (0)

  // One K-tile, one barrier.  Stage u+1 into cb^1 first (WAR certified by
  // previous tile's end-BAR), then 16 ds_reads of cb, counted-lgkm MMA,
  // VMC0 (stages ~2 MMA-clusters old), BAR.
#define TILE(cb, u, DO_S, VMCX)                                            \
  do {                                                                     \
    if (DO_S) { STAGE_A((cb) ^ 1, (u) + 1); STAGE_B((cb) ^ 1, (u) + 1); }  \
    RD_B2(cb); RD_A1(cb, 0); FEN();                                        \
    RD_A1(cb, 1); FEN();                                                   \
    LGKM4(); MMA8(0);                                                      \
    LGKM0(); MMA8(1);                                                      \
    VMCX; BAR();                                                           \
  } while (0)

  // ---- prologue: stage tile 0 -> buf0 ----
  STAGE_A(0, 0); STAGE_B(0, 0);
  VMC0();
  BAR();

  // ---- main loop: 64 K-tiles ----
  for (int u = 0; u < 62; u += 2) {
    TILE(0, u, 1, VMC0());
    TILE(1, u + 1, 1, VMC0());
  }
  TILE(0, 62, 1, VMC0());   // stages tile 63 -> buf1
  TILE(1, 63, 0, NOVM());   // last tile: no staging

  // ---- C write + bias (32x32 D: col = lane&31, row = (r&3)+8*(r>>2)+4*(lane>>5)) ----
  float* Cb = C + (size_t)(bm * 128 + wm * 64) * N + bn * 128 + wn * 64;
#pragma unroll
  for (int cg = 0; cg < 2; ++cg) {
    int n = cg * 32 + l31;
    float bv = bias[bn * 128 + wn * 64 + n];
#pragma unroll
    for (int rg = 0; rg < 2; ++rg) {
#pragma unroll
      for (int r = 0; r < 16; ++r) {
        int row = rg * 32 + (r & 3) + 8 * (r >> 2) + 4 * lk2;
        Cb[(size_t)row * N + n] = acc[rg][cg][r] + bv;
      }
    }
  }
}

extern "C" void kernel_launch(void* const* d_in, const int* in_sizes, int n_in,
                              void* d_out, int out_size, void* d_ws, size_t ws_size,
                              hipStream_t stream) {
  const float* x = (const float*)d_in[0];     // [4,2048,4096] fp32
  const float* wt = (const float*)d_in[1];    // [4096,4096] fp32
  const float* bias = (const float*)d_in[2];  // [4096] fp32
  float* out = (float*)d_out;                 // [4,2048,4096] fp32

  const int DIN = 4096;
  const int NW = in_sizes[1];                 // 16777216
  const int M = in_sizes[0] / DIN;            // 8192

  char* ws = (char*)d_ws;
  unsigned* amax_bits = (unsigned*)ws;
  ushort_t* qw = (ushort_t*)(ws + 256);                    // bf16 [4096][4096]
  ushort_t* xb = (ushort_t*)(ws + 256 + (size_t)NW * 2);   // bf16 [8192][4096]

  hipMemsetAsync(amax_bits, 0, 4, stream);
  hipLaunchKernelGGL(amax_abs_kernel, dim3(1024), dim3(256), 0, stream,
                     wt, NW / 4, amax_bits);
  hipLaunchKernelGGL(quant_weight_kernel, dim3(2048), dim3(256), 0, stream,
                     wt, amax_bits, qw, NW / 4);
  hipLaunchKernelGGL(cvt_bf16_kernel, dim3(2048), dim3(256), 0, stream,
                     x, xb, (M * DIN) / 4);

  // (8192/128) x (4096/128) = 64 x 32 = 2048 blocks of 256 threads
  hipLaunchKernelGGL(gemm128_2b, dim3(2048), dim3(256), 0, stream,
                     xb, qw, bias, out);
}